// Round 4
// baseline (1811.818 us; speedup 1.0000x reference)
//
#include <hip/hip_runtime.h>
#include <hip/hip_bf16.h>

#define N_NODES 50000
#define E_EDGES 800000
#define IN_DIM  256
#define HID     128
#define FEAT_IN 266
#define EHID    64
#define NEG     0.2f
#define PRIOR_LOG (-1.0986122886681098f)  // log(1/3 + 1e-12)
#define NB_SCAN 196                        // ceil(50000/256)

// ---------------- weight transpose: W[R][C] -> WT[C][R] ----------------
__global__ void k_transpose(const float* __restrict__ W, float* __restrict__ WT, int R, int C) {
  int i = blockIdx.x * 256 + threadIdx.x;
  if (i < R * C) {
    int r = i / C, c = i - r * C;
    WT[c * R + r] = W[i];
  }
}

// Wuv^T[f][k]: k<64 -> Wm1[k][f] (u part), k>=64 -> Wm1[k-64][128+f] (v part)
__global__ void k_makewuv(const float* __restrict__ Wm1, float* __restrict__ WuvT) {
  int i = blockIdx.x * 256 + threadIdx.x;
  if (i < 128 * 128) {
    int f = i >> 7, k = i & 127;
    WuvT[i] = (k < 64) ? Wm1[k * 256 + f] : Wm1[(k - 64) * 256 + 128 + f];
  }
}

// ---------------- CSR build (dst-grouped, stores original edge id) ----------------
__global__ void k_deg(const int* __restrict__ ei, int* __restrict__ deg) {
  int e = blockIdx.x * 256 + threadIdx.x;
  if (e < E_EDGES) atomicAdd(&deg[ei[E_EDGES + e]], 1);
}

__global__ void k_scan1(const int* __restrict__ deg, int* __restrict__ rowptr,
                        int* __restrict__ bsum) {
  __shared__ int sh[256];
  int t = threadIdx.x, i = blockIdx.x * 256 + t;
  int v = (i < N_NODES) ? deg[i] : 0;
  sh[t] = v;
  __syncthreads();
  for (int off = 1; off < 256; off <<= 1) {
    int x = (t >= off) ? sh[t - off] : 0;
    __syncthreads();
    sh[t] += x;
    __syncthreads();
  }
  if (i < N_NODES) rowptr[i] = sh[t] - v;
  if (t == 255) bsum[blockIdx.x] = sh[255];
}

__global__ void k_scan2(const int* __restrict__ bsum, int* __restrict__ boff,
                        int* __restrict__ rowptr) {
  __shared__ int sh[256];
  int t = threadIdx.x;
  int v = (t < NB_SCAN) ? bsum[t] : 0;
  sh[t] = v;
  __syncthreads();
  for (int off = 1; off < 256; off <<= 1) {
    int x = (t >= off) ? sh[t - off] : 0;
    __syncthreads();
    sh[t] += x;
    __syncthreads();
  }
  if (t < NB_SCAN) boff[t] = sh[t] - v;
  if (t == NB_SCAN - 1) rowptr[N_NODES] = sh[t];
}

__global__ void k_scan3(int* __restrict__ rowptr, const int* __restrict__ boff) {
  int i = blockIdx.x * 256 + threadIdx.x;
  if (i < N_NODES) rowptr[i] += boff[i >> 8];
}

__global__ void k_fill(const int* __restrict__ ei, const int* __restrict__ rowptr,
                       int* __restrict__ fill, int* __restrict__ eid) {
  int e = blockIdx.x * 256 + threadIdx.x;
  if (e < E_EDGES) {
    int d = ei[E_EDGES + e];
    int slot = atomicAdd(&fill[d], 1);
    eid[rowptr[d] + slot] = e;
  }
}

// ---------------- GEMM1: hx = [x | onehot(y)*mask] @ W1^T ----------------
__global__ __launch_bounds__(256) void k_gemm1(
    const float* __restrict__ x, const int* __restrict__ y, const int* __restrict__ mask,
    const float* __restrict__ W1T, float* __restrict__ hx) {
  __shared__ float xs[32][268];
  int b0 = blockIdx.x * 32;
  int t = threadIdx.x;
  {
    int c4 = t & 63, rb = t >> 6;
    for (int i = 0; i < 8; ++i) {
      int r = rb * 8 + i;
      int row = b0 + r;
      float4 v = make_float4(0.f, 0.f, 0.f, 0.f);
      if (row < N_NODES) v = *(const float4*)&x[(size_t)row * IN_DIM + c4 * 4];
      *(float4*)&xs[r][c4 * 4] = v;
    }
  }
  for (int s = t; s < 32 * 12; s += 256) {
    int r = s / 12, c = s - r * 12;
    int row = b0 + r;
    float v = 0.f;
    if (c < 10 && row < N_NODES)
      v = (mask[row] != 0 && y[row] == c) ? 1.f : 0.f;
    xs[r][256 + c] = v;
  }
  __syncthreads();

  int lane = t & 63, wv = t >> 6;
  int r0 = wv * 8;
  int k0 = lane, k1 = lane + 64;
  float acc0[8], acc1[8];
#pragma unroll
  for (int i = 0; i < 8; ++i) { acc0[i] = 0.f; acc1[i] = 0.f; }

  for (int f = 0; f < 264; f += 4) {
    float wa0 = W1T[(f + 0) * HID + k0], wb0 = W1T[(f + 0) * HID + k1];
    float wa1 = W1T[(f + 1) * HID + k0], wb1 = W1T[(f + 1) * HID + k1];
    float wa2 = W1T[(f + 2) * HID + k0], wb2 = W1T[(f + 2) * HID + k1];
    float wa3 = W1T[(f + 3) * HID + k0], wb3 = W1T[(f + 3) * HID + k1];
#pragma unroll
    for (int i = 0; i < 8; ++i) {
      float4 xv = *(float4*)&xs[r0 + i][f];
      float a = acc0[i], b = acc1[i];
      a = fmaf(xv.x, wa0, a); b = fmaf(xv.x, wb0, b);
      a = fmaf(xv.y, wa1, a); b = fmaf(xv.y, wb1, b);
      a = fmaf(xv.z, wa2, a); b = fmaf(xv.z, wb2, b);
      a = fmaf(xv.w, wa3, a); b = fmaf(xv.w, wb3, b);
      acc0[i] = a; acc1[i] = b;
    }
  }
  for (int f = 264; f < 266; ++f) {
    float wa = W1T[f * HID + k0], wb = W1T[f * HID + k1];
#pragma unroll
    for (int i = 0; i < 8; ++i) {
      float xv = xs[r0 + i][f];
      acc0[i] = fmaf(xv, wa, acc0[i]);
      acc1[i] = fmaf(xv, wb, acc1[i]);
    }
  }
#pragma unroll
  for (int i = 0; i < 8; ++i) {
    int row = b0 + r0 + i;
    if (row < N_NODES) {
      hx[(size_t)row * HID + k0] = acc0[i];
      hx[(size_t)row * HID + k1] = acc1[i];
    }
  }
}

// ---------------- GEMM2: hx2 = relu(in + b1) @ W2^T ----------------
__global__ __launch_bounds__(256) void k_gemm2(
    const float* __restrict__ in, const float* __restrict__ b1,
    const float* __restrict__ W2T, float* __restrict__ hx) {
  __shared__ float xs[64][128];
  int b0 = blockIdx.x * 64;
  int t = threadIdx.x;
  {
    int c4 = t & 31, rb = t >> 5;
    for (int i = 0; i < 8; ++i) {
      int r = rb * 8 + i;
      int row = b0 + r;
      float4 v = make_float4(0.f, 0.f, 0.f, 0.f);
      if (row < N_NODES) {
        v = *(const float4*)&in[(size_t)row * HID + c4 * 4];
        float4 bb = *(const float4*)&b1[c4 * 4];
        v.x = fmaxf(v.x + bb.x, 0.f); v.y = fmaxf(v.y + bb.y, 0.f);
        v.z = fmaxf(v.z + bb.z, 0.f); v.w = fmaxf(v.w + bb.w, 0.f);
      }
      *(float4*)&xs[r][c4 * 4] = v;
    }
  }
  __syncthreads();

  int lane = t & 63, wv = t >> 6;
  int r0 = wv * 16;
  int k0 = lane, k1 = lane + 64;
  float acc0[16], acc1[16];
#pragma unroll
  for (int i = 0; i < 16; ++i) { acc0[i] = 0.f; acc1[i] = 0.f; }

  for (int f = 0; f < 128; f += 4) {
    float wa0 = W2T[(f + 0) * HID + k0], wb0 = W2T[(f + 0) * HID + k1];
    float wa1 = W2T[(f + 1) * HID + k0], wb1 = W2T[(f + 1) * HID + k1];
    float wa2 = W2T[(f + 2) * HID + k0], wb2 = W2T[(f + 2) * HID + k1];
    float wa3 = W2T[(f + 3) * HID + k0], wb3 = W2T[(f + 3) * HID + k1];
#pragma unroll
    for (int i = 0; i < 16; ++i) {
      float4 xv = *(float4*)&xs[r0 + i][f];
      float a = acc0[i], b = acc1[i];
      a = fmaf(xv.x, wa0, a); b = fmaf(xv.x, wb0, b);
      a = fmaf(xv.y, wa1, a); b = fmaf(xv.y, wb1, b);
      a = fmaf(xv.z, wa2, a); b = fmaf(xv.z, wb2, b);
      a = fmaf(xv.w, wa3, a); b = fmaf(xv.w, wb3, b);
      acc0[i] = a; acc1[i] = b;
    }
  }
#pragma unroll
  for (int i = 0; i < 16; ++i) {
    int row = b0 + r0 + i;
    if (row < N_NODES) {
      hx[(size_t)row * HID + k0] = acc0[i];
      hx[(size_t)row * HID + k1] = acc1[i];
    }
  }
}

// ---------------- GEMM_uv: uv = h2 @ Wuv^T (+bm1 on v half) ----------------
__global__ __launch_bounds__(256) void k_gemm_uv(
    const float* __restrict__ in, const float* __restrict__ WuvT,
    const float* __restrict__ bm1, float* __restrict__ out) {
  __shared__ float xs[64][128];
  int b0 = blockIdx.x * 64;
  int t = threadIdx.x;
  {
    int c4 = t & 31, rb = t >> 5;
    for (int i = 0; i < 8; ++i) {
      int r = rb * 8 + i;
      int row = b0 + r;
      float4 v = make_float4(0.f, 0.f, 0.f, 0.f);
      if (row < N_NODES) v = *(const float4*)&in[(size_t)row * HID + c4 * 4];
      *(float4*)&xs[r][c4 * 4] = v;
    }
  }
  __syncthreads();

  int lane = t & 63, wv = t >> 6;
  int r0 = wv * 16;
  int k0 = lane, k1 = lane + 64;
  float acc0[16], acc1[16];
#pragma unroll
  for (int i = 0; i < 16; ++i) { acc0[i] = 0.f; acc1[i] = 0.f; }

  for (int f = 0; f < 128; f += 4) {
    float wa0 = WuvT[(f + 0) * HID + k0], wb0 = WuvT[(f + 0) * HID + k1];
    float wa1 = WuvT[(f + 1) * HID + k0], wb1 = WuvT[(f + 1) * HID + k1];
    float wa2 = WuvT[(f + 2) * HID + k0], wb2 = WuvT[(f + 2) * HID + k1];
    float wa3 = WuvT[(f + 3) * HID + k0], wb3 = WuvT[(f + 3) * HID + k1];
#pragma unroll
    for (int i = 0; i < 16; ++i) {
      float4 xv = *(float4*)&xs[r0 + i][f];
      float a = acc0[i], b = acc1[i];
      a = fmaf(xv.x, wa0, a); b = fmaf(xv.x, wb0, b);
      a = fmaf(xv.y, wa1, a); b = fmaf(xv.y, wb1, b);
      a = fmaf(xv.z, wa2, a); b = fmaf(xv.z, wb2, b);
      a = fmaf(xv.w, wa3, a); b = fmaf(xv.w, wb3, b);
      acc0[i] = a; acc1[i] = b;
    }
  }
  float bv = bm1[lane];
#pragma unroll
  for (int i = 0; i < 16; ++i) {
    int row = b0 + r0 + i;
    if (row < N_NODES) {
      out[(size_t)row * HID + k0] = acc0[i];        // u part
      out[(size_t)row * HID + k1] = acc1[i] + bv;   // v part (+bm1)
    }
  }
}

// ---------------- alpha_s / alpha_d ----------------
__global__ __launch_bounds__(256) void k_alpha(
    const float* __restrict__ hx, const float* __restrict__ a_s, const float* __restrict__ a_d,
    float* __restrict__ as_, float* __restrict__ ad_) {
  int gw = (blockIdx.x * 256 + threadIdx.x) >> 6;
  int lane = threadIdx.x & 63;
  if (gw >= N_NODES) return;
  float h0 = hx[(size_t)gw * HID + lane], h1 = hx[(size_t)gw * HID + 64 + lane];
  float ps = h0 * a_s[lane] + h1 * a_s[64 + lane];
  float pd = h0 * a_d[lane] + h1 * a_d[64 + lane];
#pragma unroll
  for (int m = 32; m; m >>= 1) {
    ps += __shfl_xor(ps, m, 64);
    pd += __shfl_xor(pd, m, 64);
  }
  if (lane == 0) { as_[gw] = ps; ad_[gw] = pd; }
}

// ---------------- fused GAT aggregation: wave per node, online softmax ----------------
// ADDB2=1: out = agg + b2 (fp32)
template <int ADDB2>
__global__ __launch_bounds__(256) void k_aggr(
    const int* __restrict__ rowptr, const int* __restrict__ eid, const int* __restrict__ ei,
    const float* __restrict__ as_, const float* __restrict__ ad_,
    const float* __restrict__ h, float* __restrict__ outf, const float* __restrict__ b2) {
  int n = (blockIdx.x * 256 + threadIdx.x) >> 6;
  int l = threadIdx.x & 63;
  if (n >= N_NODES) return;
  int base = rowptr[n], end = rowptr[n + 1];
  float adn = ad_[n];
  float m = -1e30f, ssum = 0.f, acc0 = 0.f, acc1 = 0.f;

  for (int c = base; c < end; c += 64) {
    int idx = c + l;
    bool valid = idx < end;
    int ev = valid ? eid[idx] : 0;
    int col = valid ? ei[ev] : 0;
    float raw = as_[col] + adn;
    float lr = raw > 0.f ? raw : NEG * raw;
    float e = valid ? lr : -1e30f;
    float cm = e;
#pragma unroll
    for (int s = 32; s; s >>= 1) cm = fmaxf(cm, __shfl_xor(cm, s, 64));
    float mn = fmaxf(m, cm);
    float scale = expf(m - mn);
    ssum *= scale; acc0 *= scale; acc1 *= scale;
    m = mn;
    float p = expf(e - m);          // invalid lanes -> 0
    float cs = p;
#pragma unroll
    for (int s = 32; s; s >>= 1) cs += __shfl_xor(cs, s, 64);
    ssum += cs;
    int cnt = end - c; if (cnt > 64) cnt = 64;
    for (int j = 0; j < cnt; ++j) {
      float pj = __shfl(p, j, 64);
      int cj = __shfl(col, j, 64);
      acc0 = fmaf(pj, h[(size_t)cj * HID + l], acc0);
      acc1 = fmaf(pj, h[(size_t)cj * HID + 64 + l], acc1);
    }
  }
  // self loop
  float raw = as_[n] + adn;
  float es = raw > 0.f ? raw : NEG * raw;
  float mn = fmaxf(m, es);
  float scale = expf(m - mn);
  ssum *= scale; acc0 *= scale; acc1 *= scale;
  float ps = expf(es - mn);
  ssum += ps;
  acc0 = fmaf(ps, h[(size_t)n * HID + l], acc0);
  acc1 = fmaf(ps, h[(size_t)n * HID + 64 + l], acc1);

  float inv = 1.f / ssum;
  if (ADDB2) {
    outf[(size_t)n * HID + l]      = acc0 * inv + b2[l];
    outf[(size_t)n * HID + 64 + l] = acc1 * inv + b2[64 + l];
  } else {
    outf[(size_t)n * HID + l]      = acc0 * inv;
    outf[(size_t)n * HID + 64 + l] = acc1 * inv;
  }
}

// ---------------- edge epilogue: wave per dst node over CSR ----------------
// hid = relu(u[src] + v[dst]); logits = Wm2 @ hid + bm2; softmax; loss
__global__ __launch_bounds__(256) void k_edge(
    const int* __restrict__ rowptr, const int* __restrict__ eid, const int* __restrict__ ei,
    const float* __restrict__ uv, const float* __restrict__ Wm2, const float* __restrict__ bm2,
    float* __restrict__ logits, float* __restrict__ probs, float* __restrict__ lacc) {
  int n = (blockIdx.x * 256 + threadIdx.x) >> 6;
  int l = threadIdx.x & 63;
  if (n >= N_NODES) return;
  int base = rowptr[n], end = rowptr[n + 1];
  if (base == end) return;
  float vn = uv[(size_t)n * HID + 64 + l];
  float w0 = Wm2[l], w1 = Wm2[64 + l], w2 = Wm2[128 + l];
  float bm20 = bm2[0], bm21 = bm2[1], bm22 = bm2[2];
  float kl = 0.f, rc = 0.f;
  float bl0 = 0.f, bl1 = 0.f, bl2 = 0.f;
  int beid = 0, cnt = 0;

  auto flush = [&](int k) {
    if (l < k) {
      float mx = fmaxf(fmaxf(bl0, bl1), bl2);
      float x0 = expf(bl0 - mx), x1 = expf(bl1 - mx), x2 = expf(bl2 - mx);
      float inv = 1.f / (x0 + x1 + x2);
      float q0 = x0 * inv, q1 = x1 * inv, q2 = x2 * inv;
      size_t o = (size_t)beid * 3;
      logits[o] = bl0; logits[o + 1] = bl1; logits[o + 2] = bl2;
      probs[o] = q0; probs[o + 1] = q1; probs[o + 2] = q2;
      kl += q0 * (logf(fmaxf(q0, 1e-12f)) - PRIOR_LOG)
          + q1 * (logf(fmaxf(q1, 1e-12f)) - PRIOR_LOG)
          + q2 * (logf(fmaxf(q2, 1e-12f)) - PRIOR_LOG);
      rc += logf(fmaxf(q0 + q2, 1e-12f));
    }
  };

  for (int cb = base; cb < end; cb += 64) {
    int idx = cb + l;
    bool valid = idx < end;
    int eidl = valid ? eid[idx] : 0;
    int srcl = valid ? ei[eidl] : 0;
    int m2 = end - cb; if (m2 > 64) m2 = 64;
    for (int j = 0; j < m2; ++j) {
      int src = __shfl(srcl, j, 64);
      int e   = __shfl(eidl, j, 64);
      float us = uv[(size_t)src * HID + l];
      float hv = fmaxf(us + vn, 0.f);
      float a = hv * w0, b = hv * w1, c = hv * w2;
#pragma unroll
      for (int m = 1; m < 64; m <<= 1) {
        a += __shfl_xor(a, m, 64);
        b += __shfl_xor(b, m, 64);
        c += __shfl_xor(c, m, 64);
      }
      if (l == cnt) { bl0 = a + bm20; bl1 = b + bm21; bl2 = c + bm22; beid = e; }
      if (++cnt == 64) { flush(64); cnt = 0; }
    }
  }
  flush(cnt);

#pragma unroll
  for (int m = 1; m < 64; m <<= 1) {
    kl += __shfl_xor(kl, m, 64);
    rc += __shfl_xor(rc, m, 64);
  }
  if (l == 0) { atomicAdd(&lacc[0], kl); atomicAdd(&lacc[1], rc); }
}

__global__ void k_loss(const float* __restrict__ lacc, float* __restrict__ out) {
  if (threadIdx.x == 0) out[0] = (lacc[0] - lacc[1]) * (1.f / (float)E_EDGES);
}

// ---------------- launcher ----------------
extern "C" void kernel_launch(void* const* d_in, const int* in_sizes, int n_in,
                              void* d_out, int out_size, void* d_ws, size_t ws_size,
                              hipStream_t stream) {
  const float* x      = (const float*)d_in[0];
  const int*   ei     = (const int*)d_in[1];
  const int*   y      = (const int*)d_in[2];
  const int*   mask   = (const int*)d_in[3];
  const float* W1     = (const float*)d_in[4];
  const float* a_src1 = (const float*)d_in[5];
  const float* a_dst1 = (const float*)d_in[6];
  const float* b1     = (const float*)d_in[7];
  const float* W2     = (const float*)d_in[8];
  const float* a_src2 = (const float*)d_in[9];
  const float* a_dst2 = (const float*)d_in[10];
  const float* b2     = (const float*)d_in[11];
  const float* Wm1    = (const float*)d_in[12];
  const float* bm1    = (const float*)d_in[13];
  const float* Wm2    = (const float*)d_in[14];
  const float* bm2    = (const float*)d_in[15];

  float* A      = (float*)d_ws;                 // hx / hx2 / uv  [N,128]
  float* Bb     = A + 6400000;                  // agg1 / h2      [N,128]
  float* as_    = Bb + 6400000;                 // [N]
  float* ad_    = as_ + 50000;                  // [N]
  int*   deg    = (int*)(ad_ + 50000);          // [N]
  int*   fill   = deg + 50000;                  // [N]
  int*   rowptr = fill + 50000;                 // [N+1]
  int*   bsum   = rowptr + 50001;               // [256]
  int*   boff   = bsum + 256;                   // [256]
  int*   eid    = boff + 256;                   // [E]
  float* W1T    = (float*)(eid + 800000);       // [266*128]
  float* W2T    = W1T + 34048;                  // [128*128]
  float* WuvT   = W2T + 16384;                  // [128*128]
  float* lacc   = WuvT + 16384;                 // [2]

  const int EBLK = (E_EDGES + 255) / 256;
  const int NWAVE = (N_NODES + 3) / 4;

  // ---- CSR build (graph fixed; reused by both layers + edge MLP) ----
  hipMemsetAsync(deg, 0, 50000 * 4, stream);
  hipMemsetAsync(fill, 0, 50000 * 4, stream);
  hipMemsetAsync(lacc, 0, 2 * 4, stream);
  k_deg<<<EBLK, 256, 0, stream>>>(ei, deg);
  k_scan1<<<NB_SCAN, 256, 0, stream>>>(deg, rowptr, bsum);
  k_scan2<<<1, 256, 0, stream>>>(bsum, boff, rowptr);
  k_scan3<<<NB_SCAN, 256, 0, stream>>>(rowptr, boff);
  k_fill<<<EBLK, 256, 0, stream>>>(ei, rowptr, fill, eid);

  // ---- weight prep ----
  k_transpose<<<(HID * FEAT_IN + 255) / 256, 256, 0, stream>>>(W1, W1T, HID, FEAT_IN);
  k_transpose<<<(HID * HID + 255) / 256, 256, 0, stream>>>(W2, W2T, HID, HID);
  k_makewuv<<<(128 * 128 + 255) / 256, 256, 0, stream>>>(Wm1, WuvT);

  // ---- layer 1 ----
  k_gemm1<<<(N_NODES + 31) / 32, 256, 0, stream>>>(x, y, mask, W1T, A);
  k_alpha<<<NWAVE, 256, 0, stream>>>(A, a_src1, a_dst1, as_, ad_);
  k_aggr<0><<<NWAVE, 256, 0, stream>>>(rowptr, eid, ei, as_, ad_, A, Bb, nullptr);

  // ---- layer 2 ----
  k_gemm2<<<(N_NODES + 63) / 64, 256, 0, stream>>>(Bb, b1, W2T, A);
  k_alpha<<<NWAVE, 256, 0, stream>>>(A, a_src2, a_dst2, as_, ad_);
  k_aggr<1><<<NWAVE, 256, 0, stream>>>(rowptr, eid, ei, as_, ad_, A, Bb, b2);  // Bb = h2 (+b2)

  // ---- per-node MLP first layer: uv = h2 @ Wuv^T ----
  k_gemm_uv<<<(N_NODES + 63) / 64, 256, 0, stream>>>(Bb, WuvT, bm1, A);        // A = uv

  // ---- per-edge epilogue + loss ----
  float* logits = (float*)d_out;
  float* probs  = logits + 2400000;
  float* lossp  = logits + 4800000;
  k_edge<<<NWAVE, 256, 0, stream>>>(rowptr, eid, ei, A, Wm2, bm2, logits, probs, lacc);
  k_loss<<<1, 64, 0, stream>>>(lacc, lossp);
}

// Round 5
// 856.646 us; speedup vs baseline: 2.1150x; 2.1150x over previous
//
#include <hip/hip_runtime.h>
#include <hip/hip_bf16.h>

#define N_NODES 50000
#define E_EDGES 800000
#define IN_DIM  256
#define HID     128
#define FEAT_IN 266
#define EHID    64
#define NEG     0.2f
#define PRIOR_LOG (-1.0986122886681098f)  // log(1/3 + 1e-12)
#define NB_SCAN 196                        // ceil(50000/256)

typedef short bf16x8 __attribute__((ext_vector_type(8)));

__device__ __forceinline__ unsigned short f2bf(float f) {
  unsigned u = __float_as_uint(f);
  u += 0x7fffu + ((u >> 16) & 1u);   // round-to-nearest-even
  return (unsigned short)(u >> 16);
}
__device__ __forceinline__ float bf2f(short s) {
  return __uint_as_float(((unsigned)(unsigned short)s) << 16);
}

// ---------------- weight transpose: W[R][C] -> WT[C][R] ----------------
__global__ void k_transpose(const float* __restrict__ W, float* __restrict__ WT, int R, int C) {
  int i = blockIdx.x * 256 + threadIdx.x;
  if (i < R * C) {
    int r = i / C, c = i - r * C;
    WT[c * R + r] = W[i];
  }
}

// Wuv^T[f][k]: k<64 -> Wm1[k][f] (u part), k>=64 -> Wm1[k-64][128+f] (v part)
__global__ void k_makewuv(const float* __restrict__ Wm1, float* __restrict__ WuvT) {
  int i = blockIdx.x * 256 + threadIdx.x;
  if (i < 128 * 128) {
    int f = i >> 7, k = i & 127;
    WuvT[i] = (k < 64) ? Wm1[k * 256 + f] : Wm1[(k - 64) * 256 + 128 + f];
  }
}

// ---------------- CSR build (dst-grouped, stores original edge id) ----------------
__global__ void k_deg(const int* __restrict__ ei, int* __restrict__ deg) {
  int e = blockIdx.x * 256 + threadIdx.x;
  if (e < E_EDGES) atomicAdd(&deg[ei[E_EDGES + e]], 1);
}

__global__ void k_scan1(const int* __restrict__ deg, int* __restrict__ rowptr,
                        int* __restrict__ bsum) {
  __shared__ int sh[256];
  int t = threadIdx.x, i = blockIdx.x * 256 + t;
  int v = (i < N_NODES) ? deg[i] : 0;
  sh[t] = v;
  __syncthreads();
  for (int off = 1; off < 256; off <<= 1) {
    int x = (t >= off) ? sh[t - off] : 0;
    __syncthreads();
    sh[t] += x;
    __syncthreads();
  }
  if (i < N_NODES) rowptr[i] = sh[t] - v;
  if (t == 255) bsum[blockIdx.x] = sh[255];
}

__global__ void k_scan2(const int* __restrict__ bsum, int* __restrict__ boff,
                        int* __restrict__ rowptr) {
  __shared__ int sh[256];
  int t = threadIdx.x;
  int v = (t < NB_SCAN) ? bsum[t] : 0;
  sh[t] = v;
  __syncthreads();
  for (int off = 1; off < 256; off <<= 1) {
    int x = (t >= off) ? sh[t - off] : 0;
    __syncthreads();
    sh[t] += x;
    __syncthreads();
  }
  if (t < NB_SCAN) boff[t] = sh[t] - v;
  if (t == NB_SCAN - 1) rowptr[N_NODES] = sh[t];
}

__global__ void k_scan3(int* __restrict__ rowptr, const int* __restrict__ boff) {
  int i = blockIdx.x * 256 + threadIdx.x;
  if (i < N_NODES) rowptr[i] += boff[i >> 8];
}

__global__ void k_fill(const int* __restrict__ ei, const int* __restrict__ rowptr,
                       int* __restrict__ fill, int* __restrict__ eid) {
  int e = blockIdx.x * 256 + threadIdx.x;
  if (e < E_EDGES) {
    int d = ei[E_EDGES + e];
    int slot = atomicAdd(&fill[d], 1);
    eid[rowptr[d] + slot] = e;
  }
}

// ---------------- GEMM1: hx = [x | onehot(y)*mask] @ W1^T ----------------
__global__ __launch_bounds__(256) void k_gemm1(
    const float* __restrict__ x, const int* __restrict__ y, const int* __restrict__ mask,
    const float* __restrict__ W1T, float* __restrict__ hx) {
  __shared__ float xs[32][268];
  int b0 = blockIdx.x * 32;
  int t = threadIdx.x;
  {
    int c4 = t & 63, rb = t >> 6;
    for (int i = 0; i < 8; ++i) {
      int r = rb * 8 + i;
      int row = b0 + r;
      float4 v = make_float4(0.f, 0.f, 0.f, 0.f);
      if (row < N_NODES) v = *(const float4*)&x[(size_t)row * IN_DIM + c4 * 4];
      *(float4*)&xs[r][c4 * 4] = v;
    }
  }
  for (int s = t; s < 32 * 12; s += 256) {
    int r = s / 12, c = s - r * 12;
    int row = b0 + r;
    float v = 0.f;
    if (c < 10 && row < N_NODES)
      v = (mask[row] != 0 && y[row] == c) ? 1.f : 0.f;
    xs[r][256 + c] = v;
  }
  __syncthreads();

  int lane = t & 63, wv = t >> 6;
  int r0 = wv * 8;
  int k0 = lane, k1 = lane + 64;
  float acc0[8], acc1[8];
#pragma unroll
  for (int i = 0; i < 8; ++i) { acc0[i] = 0.f; acc1[i] = 0.f; }

  for (int f = 0; f < 264; f += 4) {
    float wa0 = W1T[(f + 0) * HID + k0], wb0 = W1T[(f + 0) * HID + k1];
    float wa1 = W1T[(f + 1) * HID + k0], wb1 = W1T[(f + 1) * HID + k1];
    float wa2 = W1T[(f + 2) * HID + k0], wb2 = W1T[(f + 2) * HID + k1];
    float wa3 = W1T[(f + 3) * HID + k0], wb3 = W1T[(f + 3) * HID + k1];
#pragma unroll
    for (int i = 0; i < 8; ++i) {
      float4 xv = *(float4*)&xs[r0 + i][f];
      float a = acc0[i], b = acc1[i];
      a = fmaf(xv.x, wa0, a); b = fmaf(xv.x, wb0, b);
      a = fmaf(xv.y, wa1, a); b = fmaf(xv.y, wb1, b);
      a = fmaf(xv.z, wa2, a); b = fmaf(xv.z, wb2, b);
      a = fmaf(xv.w, wa3, a); b = fmaf(xv.w, wb3, b);
      acc0[i] = a; acc1[i] = b;
    }
  }
  for (int f = 264; f < 266; ++f) {
    float wa = W1T[f * HID + k0], wb = W1T[f * HID + k1];
#pragma unroll
    for (int i = 0; i < 8; ++i) {
      float xv = xs[r0 + i][f];
      acc0[i] = fmaf(xv, wa, acc0[i]);
      acc1[i] = fmaf(xv, wb, acc1[i]);
    }
  }
#pragma unroll
  for (int i = 0; i < 8; ++i) {
    int row = b0 + r0 + i;
    if (row < N_NODES) {
      hx[(size_t)row * HID + k0] = acc0[i];
      hx[(size_t)row * HID + k1] = acc1[i];
    }
  }
}

// ---------------- GEMM2: hx2 = relu(in + b1) @ W2^T ----------------
__global__ __launch_bounds__(256) void k_gemm2(
    const float* __restrict__ in, const float* __restrict__ b1,
    const float* __restrict__ W2T, float* __restrict__ hx) {
  __shared__ float xs[64][128];
  int b0 = blockIdx.x * 64;
  int t = threadIdx.x;
  {
    int c4 = t & 31, rb = t >> 5;
    for (int i = 0; i < 8; ++i) {
      int r = rb * 8 + i;
      int row = b0 + r;
      float4 v = make_float4(0.f, 0.f, 0.f, 0.f);
      if (row < N_NODES) {
        v = *(const float4*)&in[(size_t)row * HID + c4 * 4];
        float4 bb = *(const float4*)&b1[c4 * 4];
        v.x = fmaxf(v.x + bb.x, 0.f); v.y = fmaxf(v.y + bb.y, 0.f);
        v.z = fmaxf(v.z + bb.z, 0.f); v.w = fmaxf(v.w + bb.w, 0.f);
      }
      *(float4*)&xs[r][c4 * 4] = v;
    }
  }
  __syncthreads();

  int lane = t & 63, wv = t >> 6;
  int r0 = wv * 16;
  int k0 = lane, k1 = lane + 64;
  float acc0[16], acc1[16];
#pragma unroll
  for (int i = 0; i < 16; ++i) { acc0[i] = 0.f; acc1[i] = 0.f; }

  for (int f = 0; f < 128; f += 4) {
    float wa0 = W2T[(f + 0) * HID + k0], wb0 = W2T[(f + 0) * HID + k1];
    float wa1 = W2T[(f + 1) * HID + k0], wb1 = W2T[(f + 1) * HID + k1];
    float wa2 = W2T[(f + 2) * HID + k0], wb2 = W2T[(f + 2) * HID + k1];
    float wa3 = W2T[(f + 3) * HID + k0], wb3 = W2T[(f + 3) * HID + k1];
#pragma unroll
    for (int i = 0; i < 16; ++i) {
      float4 xv = *(float4*)&xs[r0 + i][f];
      float a = acc0[i], b = acc1[i];
      a = fmaf(xv.x, wa0, a); b = fmaf(xv.x, wb0, b);
      a = fmaf(xv.y, wa1, a); b = fmaf(xv.y, wb1, b);
      a = fmaf(xv.z, wa2, a); b = fmaf(xv.z, wb2, b);
      a = fmaf(xv.w, wa3, a); b = fmaf(xv.w, wb3, b);
      acc0[i] = a; acc1[i] = b;
    }
  }
#pragma unroll
  for (int i = 0; i < 16; ++i) {
    int row = b0 + r0 + i;
    if (row < N_NODES) {
      hx[(size_t)row * HID + k0] = acc0[i];
      hx[(size_t)row * HID + k1] = acc1[i];
    }
  }
}

// ---------------- GEMM_uv: uvb(bf16) = h2 @ Wuv^T (+bm1 on v half) ----------------
__global__ __launch_bounds__(256) void k_gemm_uv(
    const float* __restrict__ in, const float* __restrict__ WuvT,
    const float* __restrict__ bm1, unsigned short* __restrict__ outb) {
  __shared__ float xs[64][128];
  int b0 = blockIdx.x * 64;
  int t = threadIdx.x;
  {
    int c4 = t & 31, rb = t >> 5;
    for (int i = 0; i < 8; ++i) {
      int r = rb * 8 + i;
      int row = b0 + r;
      float4 v = make_float4(0.f, 0.f, 0.f, 0.f);
      if (row < N_NODES) v = *(const float4*)&in[(size_t)row * HID + c4 * 4];
      *(float4*)&xs[r][c4 * 4] = v;
    }
  }
  __syncthreads();

  int lane = t & 63, wv = t >> 6;
  int r0 = wv * 16;
  int k0 = lane, k1 = lane + 64;
  float acc0[16], acc1[16];
#pragma unroll
  for (int i = 0; i < 16; ++i) { acc0[i] = 0.f; acc1[i] = 0.f; }

  for (int f = 0; f < 128; f += 4) {
    float wa0 = WuvT[(f + 0) * HID + k0], wb0 = WuvT[(f + 0) * HID + k1];
    float wa1 = WuvT[(f + 1) * HID + k0], wb1 = WuvT[(f + 1) * HID + k1];
    float wa2 = WuvT[(f + 2) * HID + k0], wb2 = WuvT[(f + 2) * HID + k1];
    float wa3 = WuvT[(f + 3) * HID + k0], wb3 = WuvT[(f + 3) * HID + k1];
#pragma unroll
    for (int i = 0; i < 16; ++i) {
      float4 xv = *(float4*)&xs[r0 + i][f];
      float a = acc0[i], b = acc1[i];
      a = fmaf(xv.x, wa0, a); b = fmaf(xv.x, wb0, b);
      a = fmaf(xv.y, wa1, a); b = fmaf(xv.y, wb1, b);
      a = fmaf(xv.z, wa2, a); b = fmaf(xv.z, wb2, b);
      a = fmaf(xv.w, wa3, a); b = fmaf(xv.w, wb3, b);
      acc0[i] = a; acc1[i] = b;
    }
  }
  float bv = bm1[lane];
#pragma unroll
  for (int i = 0; i < 16; ++i) {
    int row = b0 + r0 + i;
    if (row < N_NODES) {
      outb[(size_t)row * HID + k0] = f2bf(acc0[i]);        // u part
      outb[(size_t)row * HID + k1] = f2bf(acc1[i] + bv);   // v part (+bm1)
    }
  }
}

// ---------------- alpha_s / alpha_d ----------------
__global__ __launch_bounds__(256) void k_alpha(
    const float* __restrict__ hx, const float* __restrict__ a_s, const float* __restrict__ a_d,
    float* __restrict__ as_, float* __restrict__ ad_) {
  int gw = (blockIdx.x * 256 + threadIdx.x) >> 6;
  int lane = threadIdx.x & 63;
  if (gw >= N_NODES) return;
  float h0 = hx[(size_t)gw * HID + lane], h1 = hx[(size_t)gw * HID + 64 + lane];
  float ps = h0 * a_s[lane] + h1 * a_s[64 + lane];
  float pd = h0 * a_d[lane] + h1 * a_d[64 + lane];
#pragma unroll
  for (int m = 32; m; m >>= 1) {
    ps += __shfl_xor(ps, m, 64);
    pd += __shfl_xor(pd, m, 64);
  }
  if (lane == 0) { as_[gw] = ps; ad_[gw] = pd; }
}

// ---------------- fused GAT aggregation: wave per node, online softmax ----------------
template <int ADDB2>
__global__ __launch_bounds__(256) void k_aggr(
    const int* __restrict__ rowptr, const int* __restrict__ eid, const int* __restrict__ ei,
    const float* __restrict__ as_, const float* __restrict__ ad_,
    const float* __restrict__ h, float* __restrict__ outf, const float* __restrict__ b2) {
  int n = (blockIdx.x * 256 + threadIdx.x) >> 6;
  int l = threadIdx.x & 63;
  if (n >= N_NODES) return;
  int base = rowptr[n], end = rowptr[n + 1];
  float adn = ad_[n];
  float m = -1e30f, ssum = 0.f, acc0 = 0.f, acc1 = 0.f;

  for (int c = base; c < end; c += 64) {
    int idx = c + l;
    bool valid = idx < end;
    int ev = valid ? eid[idx] : 0;
    int col = valid ? ei[ev] : 0;
    float raw = as_[col] + adn;
    float lr = raw > 0.f ? raw : NEG * raw;
    float e = valid ? lr : -1e30f;
    float cm = e;
#pragma unroll
    for (int s = 32; s; s >>= 1) cm = fmaxf(cm, __shfl_xor(cm, s, 64));
    float mn = fmaxf(m, cm);
    float scale = expf(m - mn);
    ssum *= scale; acc0 *= scale; acc1 *= scale;
    m = mn;
    float p = expf(e - m);          // invalid lanes -> 0
    float cs = p;
#pragma unroll
    for (int s = 32; s; s >>= 1) cs += __shfl_xor(cs, s, 64);
    ssum += cs;
    int cnt = end - c; if (cnt > 64) cnt = 64;
    for (int j = 0; j < cnt; ++j) {
      float pj = __shfl(p, j, 64);
      int cj = __shfl(col, j, 64);
      acc0 = fmaf(pj, h[(size_t)cj * HID + l], acc0);
      acc1 = fmaf(pj, h[(size_t)cj * HID + 64 + l], acc1);
    }
  }
  // self loop
  float raw = as_[n] + adn;
  float es = raw > 0.f ? raw : NEG * raw;
  float mn = fmaxf(m, es);
  float scale = expf(m - mn);
  ssum *= scale; acc0 *= scale; acc1 *= scale;
  float ps = expf(es - mn);
  ssum += ps;
  acc0 = fmaf(ps, h[(size_t)n * HID + l], acc0);
  acc1 = fmaf(ps, h[(size_t)n * HID + 64 + l], acc1);

  float inv = 1.f / ssum;
  if (ADDB2) {
    outf[(size_t)n * HID + l]      = acc0 * inv + b2[l];
    outf[(size_t)n * HID + 64 + l] = acc1 * inv + b2[64 + l];
  } else {
    outf[(size_t)n * HID + l]      = acc0 * inv;
    outf[(size_t)n * HID + 64 + l] = acc1 * inv;
  }
}

// ---------------- edge epilogue: lane = edge, original edge order ----------------
// hid = relu(u[src] + v[dst]); logits = Wm2 @ hid + bm2; softmax; loss
__global__ __launch_bounds__(256) void k_edge(
    const int* __restrict__ ei, const unsigned short* __restrict__ uvb,
    const float* __restrict__ Wm2, const float* __restrict__ bm2,
    float* __restrict__ logits, float* __restrict__ probs, float* __restrict__ lacc) {
  __shared__ float4 wl[64];
  int t = threadIdx.x;
  if (t < 64) wl[t] = make_float4(Wm2[t], Wm2[64 + t], Wm2[128 + t], 0.f);
  __syncthreads();

  int e = blockIdx.x * 256 + t;
  int src = ei[e], dst = ei[E_EDGES + e];
  const bf16x8* pu = (const bf16x8*)(uvb + (size_t)src * HID);
  const bf16x8* pv = (const bf16x8*)(uvb + (size_t)dst * HID + 64);

  float a0 = 0.f, a1 = 0.f, a2 = 0.f;
#pragma unroll
  for (int c = 0; c < 8; ++c) {
    bf16x8 uu = pu[c];
    bf16x8 vv = pv[c];
#pragma unroll
    for (int j = 0; j < 8; ++j) {
      float hv = fmaxf(bf2f(uu[j]) + bf2f(vv[j]), 0.f);
      float4 w = wl[c * 8 + j];
      a0 = fmaf(hv, w.x, a0);
      a1 = fmaf(hv, w.y, a1);
      a2 = fmaf(hv, w.z, a2);
    }
  }
  float l0 = a0 + bm2[0], l1 = a1 + bm2[1], l2 = a2 + bm2[2];
  float mx = fmaxf(fmaxf(l0, l1), l2);
  float x0 = expf(l0 - mx), x1 = expf(l1 - mx), x2 = expf(l2 - mx);
  float inv = 1.f / (x0 + x1 + x2);
  float q0 = x0 * inv, q1 = x1 * inv, q2 = x2 * inv;
  size_t o = (size_t)e * 3;
  logits[o] = l0; logits[o + 1] = l1; logits[o + 2] = l2;
  probs[o] = q0; probs[o + 1] = q1; probs[o + 2] = q2;

  float kl = q0 * (logf(fmaxf(q0, 1e-12f)) - PRIOR_LOG)
           + q1 * (logf(fmaxf(q1, 1e-12f)) - PRIOR_LOG)
           + q2 * (logf(fmaxf(q2, 1e-12f)) - PRIOR_LOG);
  float rc = logf(fmaxf(q0 + q2, 1e-12f));
#pragma unroll
  for (int m = 1; m < 64; m <<= 1) {
    kl += __shfl_xor(kl, m, 64);
    rc += __shfl_xor(rc, m, 64);
  }
  if ((t & 63) == 0) { atomicAdd(&lacc[0], kl); atomicAdd(&lacc[1], rc); }
}

__global__ void k_loss(const float* __restrict__ lacc, float* __restrict__ out) {
  if (threadIdx.x == 0) out[0] = (lacc[0] - lacc[1]) * (1.f / (float)E_EDGES);
}

// ---------------- launcher ----------------
extern "C" void kernel_launch(void* const* d_in, const int* in_sizes, int n_in,
                              void* d_out, int out_size, void* d_ws, size_t ws_size,
                              hipStream_t stream) {
  const float* x      = (const float*)d_in[0];
  const int*   ei     = (const int*)d_in[1];
  const int*   y      = (const int*)d_in[2];
  const int*   mask   = (const int*)d_in[3];
  const float* W1     = (const float*)d_in[4];
  const float* a_src1 = (const float*)d_in[5];
  const float* a_dst1 = (const float*)d_in[6];
  const float* b1     = (const float*)d_in[7];
  const float* W2     = (const float*)d_in[8];
  const float* a_src2 = (const float*)d_in[9];
  const float* a_dst2 = (const float*)d_in[10];
  const float* b2     = (const float*)d_in[11];
  const float* Wm1    = (const float*)d_in[12];
  const float* bm1    = (const float*)d_in[13];
  const float* Wm2    = (const float*)d_in[14];
  const float* bm2    = (const float*)d_in[15];

  float* A      = (float*)d_ws;                 // hx / hx2        [N,128]
  float* Bb     = A + 6400000;                  // agg1 / h2       [N,128]
  float* as_    = Bb + 6400000;                 // [N]
  float* ad_    = as_ + 50000;                  // [N]
  int*   deg    = (int*)(ad_ + 50000);          // [N]
  int*   fill   = deg + 50000;                  // [N]
  int*   rowptr = fill + 50000;                 // [N+1]
  int*   bsum   = rowptr + 50001;               // [256]
  int*   boff   = bsum + 256;                   // [256]
  int*   eid    = boff + 256;                   // [E]
  float* W1T    = (float*)(eid + 800000);       // [266*128]
  float* W2T    = W1T + 34048;                  // [128*128]
  float* WuvT   = W2T + 16384;                  // [128*128]
  float* lacc   = WuvT + 16384;                 // [2]
  unsigned short* uvb = (unsigned short*)A;     // bf16 uv (aliases A; A dead by then)

  const int EBLK = (E_EDGES + 255) / 256;
  const int NWAVE = (N_NODES + 3) / 4;

  // ---- CSR build (graph fixed; used by k_aggr) ----
  hipMemsetAsync(deg, 0, 50000 * 4, stream);
  hipMemsetAsync(fill, 0, 50000 * 4, stream);
  hipMemsetAsync(lacc, 0, 2 * 4, stream);
  k_deg<<<EBLK, 256, 0, stream>>>(ei, deg);
  k_scan1<<<NB_SCAN, 256, 0, stream>>>(deg, rowptr, bsum);
  k_scan2<<<1, 256, 0, stream>>>(bsum, boff, rowptr);
  k_scan3<<<NB_SCAN, 256, 0, stream>>>(rowptr, boff);
  k_fill<<<EBLK, 256, 0, stream>>>(ei, rowptr, fill, eid);

  // ---- weight prep ----
  k_transpose<<<(HID * FEAT_IN + 255) / 256, 256, 0, stream>>>(W1, W1T, HID, FEAT_IN);
  k_transpose<<<(HID * HID + 255) / 256, 256, 0, stream>>>(W2, W2T, HID, HID);
  k_makewuv<<<(128 * 128 + 255) / 256, 256, 0, stream>>>(Wm1, WuvT);

  // ---- layer 1 ----
  k_gemm1<<<(N_NODES + 31) / 32, 256, 0, stream>>>(x, y, mask, W1T, A);
  k_alpha<<<NWAVE, 256, 0, stream>>>(A, a_src1, a_dst1, as_, ad_);
  k_aggr<0><<<NWAVE, 256, 0, stream>>>(rowptr, eid, ei, as_, ad_, A, Bb, nullptr);

  // ---- layer 2 ----
  k_gemm2<<<(N_NODES + 63) / 64, 256, 0, stream>>>(Bb, b1, W2T, A);
  k_alpha<<<NWAVE, 256, 0, stream>>>(A, a_src2, a_dst2, as_, ad_);
  k_aggr<1><<<NWAVE, 256, 0, stream>>>(rowptr, eid, ei, as_, ad_, A, Bb, b2);  // Bb = h2 (+b2)

  // ---- per-node MLP first layer: uvb = bf16(h2 @ Wuv^T) ----
  k_gemm_uv<<<(N_NODES + 63) / 64, 256, 0, stream>>>(Bb, WuvT, bm1, uvb);

  // ---- per-edge epilogue + loss (lane = edge, original order) ----
  float* logits = (float*)d_out;
  float* probs  = logits + 2400000;
  float* lossp  = logits + 4800000;
  k_edge<<<E_EDGES / 256, 256, 0, stream>>>(ei, uvb, Wm2, bm2, logits, probs, lacc);
  k_loss<<<1, 64, 0, stream>>>(lacc, lossp);
}

// Round 7
// 838.607 us; speedup vs baseline: 2.1605x; 1.0215x over previous
//
#include <hip/hip_runtime.h>
#include <hip/hip_bf16.h>

#define N_NODES 50000
#define E_EDGES 800000
#define IN_DIM  256
#define HID     128
#define FEAT_IN 266
#define EHID    64
#define NEG     0.2f
#define PRIOR_LOG (-1.0986122886681098f)  // log(1/3 + 1e-12)
#define NB_SCAN 196                        // ceil(50000/256)

typedef short bf16x8 __attribute__((ext_vector_type(8)));

__device__ __forceinline__ unsigned short f2bf(float f) {
  unsigned u = __float_as_uint(f);
  u += 0x7fffu + ((u >> 16) & 1u);   // round-to-nearest-even
  return (unsigned short)(u >> 16);
}
__device__ __forceinline__ float bf2f(short s) {
  return __uint_as_float(((unsigned)(unsigned short)s) << 16);
}

// ---------------- weight transpose: W[R][C] -> WT[C][R] ----------------
__global__ void k_transpose(const float* __restrict__ W, float* __restrict__ WT, int R, int C) {
  int i = blockIdx.x * 256 + threadIdx.x;
  if (i < R * C) {
    int r = i / C, c = i - r * C;
    WT[c * R + r] = W[i];
  }
}

// Wuv^T[f][k]: k<64 -> Wm1[k][f] (u part), k>=64 -> Wm1[k-64][128+f] (v part)
__global__ void k_makewuv(const float* __restrict__ Wm1, float* __restrict__ WuvT) {
  int i = blockIdx.x * 256 + threadIdx.x;
  if (i < 128 * 128) {
    int f = i >> 7, k = i & 127;
    WuvT[i] = (k < 64) ? Wm1[k * 256 + f] : Wm1[(k - 64) * 256 + 128 + f];
  }
}

// ---------------- CSR build (dst-grouped, stores original edge id) ----------------
__global__ void k_deg(const int* __restrict__ ei, int* __restrict__ deg) {
  int e = blockIdx.x * 256 + threadIdx.x;
  if (e < E_EDGES) atomicAdd(&deg[ei[E_EDGES + e]], 1);
}

__global__ void k_scan1(const int* __restrict__ deg, int* __restrict__ rowptr,
                        int* __restrict__ bsum) {
  __shared__ int sh[256];
  int t = threadIdx.x, i = blockIdx.x * 256 + t;
  int v = (i < N_NODES) ? deg[i] : 0;
  sh[t] = v;
  __syncthreads();
  for (int off = 1; off < 256; off <<= 1) {
    int x = (t >= off) ? sh[t - off] : 0;
    __syncthreads();
    sh[t] += x;
    __syncthreads();
  }
  if (i < N_NODES) rowptr[i] = sh[t] - v;
  if (t == 255) bsum[blockIdx.x] = sh[255];
}

__global__ void k_scan2(const int* __restrict__ bsum, int* __restrict__ boff,
                        int* __restrict__ rowptr) {
  __shared__ int sh[256];
  int t = threadIdx.x;
  int v = (t < NB_SCAN) ? bsum[t] : 0;
  sh[t] = v;
  __syncthreads();
  for (int off = 1; off < 256; off <<= 1) {
    int x = (t >= off) ? sh[t - off] : 0;
    __syncthreads();
    sh[t] += x;
    __syncthreads();
  }
  if (t < NB_SCAN) boff[t] = sh[t] - v;
  if (t == NB_SCAN - 1) rowptr[N_NODES] = sh[t];
}

__global__ void k_scan3(int* __restrict__ rowptr, const int* __restrict__ boff) {
  int i = blockIdx.x * 256 + threadIdx.x;
  if (i < N_NODES) rowptr[i] += boff[i >> 8];
}

__global__ void k_fill(const int* __restrict__ ei, const int* __restrict__ rowptr,
                       int* __restrict__ fill, int* __restrict__ eid) {
  int e = blockIdx.x * 256 + threadIdx.x;
  if (e < E_EDGES) {
    int d = ei[E_EDGES + e];
    int slot = atomicAdd(&fill[d], 1);
    eid[rowptr[d] + slot] = e;
  }
}

// ---------------- GEMM1: hx = [x | onehot(y)*mask] @ W1^T ----------------
__global__ __launch_bounds__(256) void k_gemm1(
    const float* __restrict__ x, const int* __restrict__ y, const int* __restrict__ mask,
    const float* __restrict__ W1T, float* __restrict__ hx) {
  __shared__ float xs[32][268];
  int b0 = blockIdx.x * 32;
  int t = threadIdx.x;
  {
    int c4 = t & 63, rb = t >> 6;
    for (int i = 0; i < 8; ++i) {
      int r = rb * 8 + i;
      int row = b0 + r;
      float4 v = make_float4(0.f, 0.f, 0.f, 0.f);
      if (row < N_NODES) v = *(const float4*)&x[(size_t)row * IN_DIM + c4 * 4];
      *(float4*)&xs[r][c4 * 4] = v;
    }
  }
  for (int s = t; s < 32 * 12; s += 256) {
    int r = s / 12, c = s - r * 12;
    int row = b0 + r;
    float v = 0.f;
    if (c < 10 && row < N_NODES)
      v = (mask[row] != 0 && y[row] == c) ? 1.f : 0.f;
    xs[r][256 + c] = v;
  }
  __syncthreads();

  int lane = t & 63, wv = t >> 6;
  int r0 = wv * 8;
  int k0 = lane, k1 = lane + 64;
  float acc0[8], acc1[8];
#pragma unroll
  for (int i = 0; i < 8; ++i) { acc0[i] = 0.f; acc1[i] = 0.f; }

  for (int f = 0; f < 264; f += 4) {
    float wa0 = W1T[(f + 0) * HID + k0], wb0 = W1T[(f + 0) * HID + k1];
    float wa1 = W1T[(f + 1) * HID + k0], wb1 = W1T[(f + 1) * HID + k1];
    float wa2 = W1T[(f + 2) * HID + k0], wb2 = W1T[(f + 2) * HID + k1];
    float wa3 = W1T[(f + 3) * HID + k0], wb3 = W1T[(f + 3) * HID + k1];
#pragma unroll
    for (int i = 0; i < 8; ++i) {
      float4 xv = *(float4*)&xs[r0 + i][f];
      float a = acc0[i], b = acc1[i];
      a = fmaf(xv.x, wa0, a); b = fmaf(xv.x, wb0, b);
      a = fmaf(xv.y, wa1, a); b = fmaf(xv.y, wb1, b);
      a = fmaf(xv.z, wa2, a); b = fmaf(xv.z, wb2, b);
      a = fmaf(xv.w, wa3, a); b = fmaf(xv.w, wb3, b);
      acc0[i] = a; acc1[i] = b;
    }
  }
  for (int f = 264; f < 266; ++f) {
    float wa = W1T[f * HID + k0], wb = W1T[f * HID + k1];
#pragma unroll
    for (int i = 0; i < 8; ++i) {
      float xv = xs[r0 + i][f];
      acc0[i] = fmaf(xv, wa, acc0[i]);
      acc1[i] = fmaf(xv, wb, acc1[i]);
    }
  }
#pragma unroll
  for (int i = 0; i < 8; ++i) {
    int row = b0 + r0 + i;
    if (row < N_NODES) {
      hx[(size_t)row * HID + k0] = acc0[i];
      hx[(size_t)row * HID + k1] = acc1[i];
    }
  }
}

// ---------------- GEMM2: hx2 = relu(in + b1) @ W2^T ----------------
__global__ __launch_bounds__(256) void k_gemm2(
    const float* __restrict__ in, const float* __restrict__ b1,
    const float* __restrict__ W2T, float* __restrict__ hx) {
  __shared__ float xs[64][128];
  int b0 = blockIdx.x * 64;
  int t = threadIdx.x;
  {
    int c4 = t & 31, rb = t >> 5;
    for (int i = 0; i < 8; ++i) {
      int r = rb * 8 + i;
      int row = b0 + r;
      float4 v = make_float4(0.f, 0.f, 0.f, 0.f);
      if (row < N_NODES) {
        v = *(const float4*)&in[(size_t)row * HID + c4 * 4];
        float4 bb = *(const float4*)&b1[c4 * 4];
        v.x = fmaxf(v.x + bb.x, 0.f); v.y = fmaxf(v.y + bb.y, 0.f);
        v.z = fmaxf(v.z + bb.z, 0.f); v.w = fmaxf(v.w + bb.w, 0.f);
      }
      *(float4*)&xs[r][c4 * 4] = v;
    }
  }
  __syncthreads();

  int lane = t & 63, wv = t >> 6;
  int r0 = wv * 16;
  int k0 = lane, k1 = lane + 64;
  float acc0[16], acc1[16];
#pragma unroll
  for (int i = 0; i < 16; ++i) { acc0[i] = 0.f; acc1[i] = 0.f; }

  for (int f = 0; f < 128; f += 4) {
    float wa0 = W2T[(f + 0) * HID + k0], wb0 = W2T[(f + 0) * HID + k1];
    float wa1 = W2T[(f + 1) * HID + k0], wb1 = W2T[(f + 1) * HID + k1];
    float wa2 = W2T[(f + 2) * HID + k0], wb2 = W2T[(f + 2) * HID + k1];
    float wa3 = W2T[(f + 3) * HID + k0], wb3 = W2T[(f + 3) * HID + k1];
#pragma unroll
    for (int i = 0; i < 16; ++i) {
      float4 xv = *(float4*)&xs[r0 + i][f];
      float a = acc0[i], b = acc1[i];
      a = fmaf(xv.x, wa0, a); b = fmaf(xv.x, wb0, b);
      a = fmaf(xv.y, wa1, a); b = fmaf(xv.y, wb1, b);
      a = fmaf(xv.z, wa2, a); b = fmaf(xv.z, wb2, b);
      a = fmaf(xv.w, wa3, a); b = fmaf(xv.w, wb3, b);
      acc0[i] = a; acc1[i] = b;
    }
  }
#pragma unroll
  for (int i = 0; i < 16; ++i) {
    int row = b0 + r0 + i;
    if (row < N_NODES) {
      hx[(size_t)row * HID + k0] = acc0[i];
      hx[(size_t)row * HID + k1] = acc1[i];
    }
  }
}

// ---------------- GEMM_uv: uvb(bf16) = h2 @ Wuv^T (+bm1 on v half) ----------------
__global__ __launch_bounds__(256) void k_gemm_uv(
    const float* __restrict__ in, const float* __restrict__ WuvT,
    const float* __restrict__ bm1, unsigned short* __restrict__ outb) {
  __shared__ float xs[64][128];
  int b0 = blockIdx.x * 64;
  int t = threadIdx.x;
  {
    int c4 = t & 31, rb = t >> 5;
    for (int i = 0; i < 8; ++i) {
      int r = rb * 8 + i;
      int row = b0 + r;
      float4 v = make_float4(0.f, 0.f, 0.f, 0.f);
      if (row < N_NODES) v = *(const float4*)&in[(size_t)row * HID + c4 * 4];
      *(float4*)&xs[r][c4 * 4] = v;
    }
  }
  __syncthreads();

  int lane = t & 63, wv = t >> 6;
  int r0 = wv * 16;
  int k0 = lane, k1 = lane + 64;
  float acc0[16], acc1[16];
#pragma unroll
  for (int i = 0; i < 16; ++i) { acc0[i] = 0.f; acc1[i] = 0.f; }

  for (int f = 0; f < 128; f += 4) {
    float wa0 = WuvT[(f + 0) * HID + k0], wb0 = WuvT[(f + 0) * HID + k1];
    float wa1 = WuvT[(f + 1) * HID + k0], wb1 = WuvT[(f + 1) * HID + k1];
    float wa2 = WuvT[(f + 2) * HID + k0], wb2 = WuvT[(f + 2) * HID + k1];
    float wa3 = WuvT[(f + 3) * HID + k0], wb3 = WuvT[(f + 3) * HID + k1];
#pragma unroll
    for (int i = 0; i < 16; ++i) {
      float4 xv = *(float4*)&xs[r0 + i][f];
      float a = acc0[i], b = acc1[i];
      a = fmaf(xv.x, wa0, a); b = fmaf(xv.x, wb0, b);
      a = fmaf(xv.y, wa1, a); b = fmaf(xv.y, wb1, b);
      a = fmaf(xv.z, wa2, a); b = fmaf(xv.z, wb2, b);
      a = fmaf(xv.w, wa3, a); b = fmaf(xv.w, wb3, b);
      acc0[i] = a; acc1[i] = b;
    }
  }
  float bv = bm1[lane];
#pragma unroll
  for (int i = 0; i < 16; ++i) {
    int row = b0 + r0 + i;
    if (row < N_NODES) {
      outb[(size_t)row * HID + k0] = f2bf(acc0[i]);        // u part
      outb[(size_t)row * HID + k1] = f2bf(acc1[i] + bv);   // v part (+bm1)
    }
  }
}

// ---------------- alpha_s / alpha_d ----------------
__global__ __launch_bounds__(256) void k_alpha(
    const float* __restrict__ hx, const float* __restrict__ a_s, const float* __restrict__ a_d,
    float* __restrict__ as_, float* __restrict__ ad_) {
  int gw = (blockIdx.x * 256 + threadIdx.x) >> 6;
  int lane = threadIdx.x & 63;
  if (gw >= N_NODES) return;
  float h0 = hx[(size_t)gw * HID + lane], h1 = hx[(size_t)gw * HID + 64 + lane];
  float ps = h0 * a_s[lane] + h1 * a_s[64 + lane];
  float pd = h0 * a_d[lane] + h1 * a_d[64 + lane];
#pragma unroll
  for (int m = 32; m; m >>= 1) {
    ps += __shfl_xor(ps, m, 64);
    pd += __shfl_xor(pd, m, 64);
  }
  if (lane == 0) { as_[gw] = ps; ad_[gw] = pd; }
}

// ---------------- fused GAT aggregation: wave per node, online softmax ----------------
// 8-row grouped gathers: 16 independent loads in flight per group (MLP, G7).
template <int ADDB2>
__global__ __launch_bounds__(256) void k_aggr(
    const int* __restrict__ rowptr, const int* __restrict__ eid, const int* __restrict__ ei,
    const float* __restrict__ as_, const float* __restrict__ ad_,
    const float* __restrict__ h, float* __restrict__ outf, const float* __restrict__ b2) {
  int n = (blockIdx.x * 256 + threadIdx.x) >> 6;
  int l = threadIdx.x & 63;
  if (n >= N_NODES) return;
  int base = rowptr[n], end = rowptr[n + 1];
  float adn = ad_[n];
  float m = -1e30f, ssum = 0.f, acc0 = 0.f, acc1 = 0.f;

  for (int c = base; c < end; c += 64) {
    int idx = c + l;
    bool valid = idx < end;
    int ev = valid ? eid[idx] : 0;
    int col = valid ? ei[ev] : 0;
    float raw = as_[col] + adn;
    float lr = raw > 0.f ? raw : NEG * raw;
    float e = valid ? lr : -1e30f;
    float cm = e;
#pragma unroll
    for (int s = 32; s; s >>= 1) cm = fmaxf(cm, __shfl_xor(cm, s, 64));
    float mn = fmaxf(m, cm);
    float scale = expf(m - mn);
    ssum *= scale; acc0 *= scale; acc1 *= scale;
    m = mn;
    float p = expf(e - m);          // invalid lanes -> 0
    float cs = p;
#pragma unroll
    for (int s = 32; s; s >>= 1) cs += __shfl_xor(cs, s, 64);
    ssum += cs;
    int cnt = end - c; if (cnt > 64) cnt = 64;
    // 8-row groups; padded rows have p==0 (and col==0), contribute nothing
    for (int j0 = 0; j0 < cnt; j0 += 8) {
      int cc[8];
      float xa[8], xb[8], pp[8];
#pragma unroll
      for (int k = 0; k < 8; ++k) cc[k] = __shfl(col, j0 + k, 64);
#pragma unroll
      for (int k = 0; k < 8; ++k) {
        xa[k] = h[(size_t)cc[k] * HID + l];
        xb[k] = h[(size_t)cc[k] * HID + 64 + l];
      }
#pragma unroll
      for (int k = 0; k < 8; ++k) pp[k] = __shfl(p, j0 + k, 64);
#pragma unroll
      for (int k = 0; k < 8; ++k) {
        acc0 = fmaf(pp[k], xa[k], acc0);
        acc1 = fmaf(pp[k], xb[k], acc1);
      }
    }
  }
  // self loop
  float raw = as_[n] + adn;
  float es = raw > 0.f ? raw : NEG * raw;
  float mn = fmaxf(m, es);
  float scale = expf(m - mn);
  ssum *= scale; acc0 *= scale; acc1 *= scale;
  float ps = expf(es - mn);
  ssum += ps;
  acc0 = fmaf(ps, h[(size_t)n * HID + l], acc0);
  acc1 = fmaf(ps, h[(size_t)n * HID + 64 + l], acc1);

  float inv = 1.f / ssum;
  if (ADDB2) {
    outf[(size_t)n * HID + l]      = acc0 * inv + b2[l];
    outf[(size_t)n * HID + 64 + l] = acc1 * inv + b2[64 + l];
  } else {
    outf[(size_t)n * HID + l]      = acc0 * inv;
    outf[(size_t)n * HID + 64 + l] = acc1 * inv;
  }
}

// ---------------- edge epilogue: lane = edge; ALL 16 gather loads hoisted ----------------
__global__ __launch_bounds__(256) void k_edge(
    const int* __restrict__ ei, const unsigned short* __restrict__ uvb,
    const float* __restrict__ Wm2, const float* __restrict__ bm2,
    float* __restrict__ logits, float* __restrict__ probs, float* __restrict__ lacc) {
  __shared__ float4 wl[64];
  int t = threadIdx.x;
  if (t < 64) wl[t] = make_float4(Wm2[t], Wm2[64 + t], Wm2[128 + t], 0.f);
  __syncthreads();

  int e = blockIdx.x * 256 + t;
  int src = ei[e], dst = ei[E_EDGES + e];
  const bf16x8* pu = (const bf16x8*)(uvb + (size_t)src * HID);
  const bf16x8* pv = (const bf16x8*)(uvb + (size_t)dst * HID + 64);

  // issue all 16 independent loads before any compute (registers: unrolled const idx)
  bf16x8 ur[8], vr[8];
#pragma unroll
  for (int c = 0; c < 8; ++c) ur[c] = pu[c];
#pragma unroll
  for (int c = 0; c < 8; ++c) vr[c] = pv[c];

  float a0 = 0.f, a1 = 0.f, a2 = 0.f;
#pragma unroll
  for (int c = 0; c < 8; ++c) {
#pragma unroll
    for (int j = 0; j < 8; ++j) {
      float hv = fmaxf(bf2f(ur[c][j]) + bf2f(vr[c][j]), 0.f);
      float4 w = wl[c * 8 + j];
      a0 = fmaf(hv, w.x, a0);
      a1 = fmaf(hv, w.y, a1);
      a2 = fmaf(hv, w.z, a2);
    }
  }
  float l0 = a0 + bm2[0], l1 = a1 + bm2[1], l2 = a2 + bm2[2];
  float mx = fmaxf(fmaxf(l0, l1), l2);
  float x0 = expf(l0 - mx), x1 = expf(l1 - mx), x2 = expf(l2 - mx);
  float inv = 1.f / (x0 + x1 + x2);
  float q0 = x0 * inv, q1 = x1 * inv, q2 = x2 * inv;
  size_t o = (size_t)e * 3;
  logits[o] = l0; logits[o + 1] = l1; logits[o + 2] = l2;
  probs[o] = q0; probs[o + 1] = q1; probs[o + 2] = q2;

  float kl = q0 * (logf(fmaxf(q0, 1e-12f)) - PRIOR_LOG)
           + q1 * (logf(fmaxf(q1, 1e-12f)) - PRIOR_LOG)
           + q2 * (logf(fmaxf(q2, 1e-12f)) - PRIOR_LOG);
  float rc = logf(fmaxf(q0 + q2, 1e-12f));
#pragma unroll
  for (int m = 1; m < 64; m <<= 1) {
    kl += __shfl_xor(kl, m, 64);
    rc += __shfl_xor(rc, m, 64);
  }
  if ((t & 63) == 0) { atomicAdd(&lacc[0], kl); atomicAdd(&lacc[1], rc); }
}

__global__ void k_loss(const float* __restrict__ lacc, float* __restrict__ out) {
  if (threadIdx.x == 0) out[0] = (lacc[0] - lacc[1]) * (1.f / (float)E_EDGES);
}

// ---------------- launcher ----------------
extern "C" void kernel_launch(void* const* d_in, const int* in_sizes, int n_in,
                              void* d_out, int out_size, void* d_ws, size_t ws_size,
                              hipStream_t stream) {
  const float* x      = (const float*)d_in[0];
  const int*   ei     = (const int*)d_in[1];
  const int*   y      = (const int*)d_in[2];
  const int*   mask   = (const int*)d_in[3];
  const float* W1     = (const float*)d_in[4];
  const float* a_src1 = (const float*)d_in[5];
  const float* a_dst1 = (const float*)d_in[6];
  const float* b1     = (const float*)d_in[7];
  const float* W2     = (const float*)d_in[8];
  const float* a_src2 = (const float*)d_in[9];
  const float* a_dst2 = (const float*)d_in[10];
  const float* b2     = (const float*)d_in[11];
  const float* Wm1    = (const float*)d_in[12];
  const float* bm1    = (const float*)d_in[13];
  const float* Wm2    = (const float*)d_in[14];
  const float* bm2    = (const float*)d_in[15];

  float* A      = (float*)d_ws;                 // hx / hx2        [N,128]
  float* Bb     = A + 6400000;                  // agg1 / h2       [N,128]
  float* as_    = Bb + 6400000;                 // [N]
  float* ad_    = as_ + 50000;                  // [N]
  int*   deg    = (int*)(ad_ + 50000);          // [N]
  int*   fill   = deg + 50000;                  // [N]
  int*   rowptr = fill + 50000;                 // [N+1]
  int*   bsum   = rowptr + 50001;               // [256]
  int*   boff   = bsum + 256;                   // [256]
  int*   eid    = boff + 256;                   // [E]
  float* W1T    = (float*)(eid + 800000);       // [266*128]
  float* W2T    = W1T + 34048;                  // [128*128]
  float* WuvT   = W2T + 16384;                  // [128*128]
  float* lacc   = WuvT + 16384;                 // [2]
  unsigned short* uvb = (unsigned short*)A;     // bf16 uv (aliases A; A dead by then)

  const int EBLK = (E_EDGES + 255) / 256;
  const int NWAVE = (N_NODES + 3) / 4;

  // ---- CSR build (graph fixed; used by k_aggr) ----
  hipMemsetAsync(deg, 0, 50000 * 4, stream);
  hipMemsetAsync(fill, 0, 50000 * 4, stream);
  hipMemsetAsync(lacc, 0, 2 * 4, stream);
  k_deg<<<EBLK, 256, 0, stream>>>(ei, deg);
  k_scan1<<<NB_SCAN, 256, 0, stream>>>(deg, rowptr, bsum);
  k_scan2<<<1, 256, 0, stream>>>(bsum, boff, rowptr);
  k_scan3<<<NB_SCAN, 256, 0, stream>>>(rowptr, boff);
  k_fill<<<EBLK, 256, 0, stream>>>(ei, rowptr, fill, eid);

  // ---- weight prep ----
  k_transpose<<<(HID * FEAT_IN + 255) / 256, 256, 0, stream>>>(W1, W1T, HID, FEAT_IN);
  k_transpose<<<(HID * HID + 255) / 256, 256, 0, stream>>>(W2, W2T, HID, HID);
  k_makewuv<<<(128 * 128 + 255) / 256, 256, 0, stream>>>(Wm1, WuvT);

  // ---- layer 1 ----
  k_gemm1<<<(N_NODES + 31) / 32, 256, 0, stream>>>(x, y, mask, W1T, A);
  k_alpha<<<NWAVE, 256, 0, stream>>>(A, a_src1, a_dst1, as_, ad_);
  k_aggr<0><<<NWAVE, 256, 0, stream>>>(rowptr, eid, ei, as_, ad_, A, Bb, nullptr);

  // ---- layer 2 ----
  k_gemm2<<<(N_NODES + 63) / 64, 256, 0, stream>>>(Bb, b1, W2T, A);
  k_alpha<<<NWAVE, 256, 0, stream>>>(A, a_src2, a_dst2, as_, ad_);
  k_aggr<1><<<NWAVE, 256, 0, stream>>>(rowptr, eid, ei, as_, ad_, A, Bb, b2);  // Bb = h2 (+b2)

  // ---- per-node MLP first layer: uvb = bf16(h2 @ Wuv^T) ----
  k_gemm_uv<<<(N_NODES + 63) / 64, 256, 0, stream>>>(Bb, WuvT, bm1, uvb);

  // ---- per-edge epilogue + loss (lane = edge, original order) ----
  float* logits = (float*)d_out;
  float* probs  = logits + 2400000;
  float* lossp  = logits + 4800000;
  k_edge<<<E_EDGES / 256, 256, 0, stream>>>(ei, uvb, Wm2, bm2, logits, probs, lacc);
  k_loss<<<1, 64, 0, stream>>>(lacc, lossp);
}